// Round 1
// 396.967 us; speedup vs baseline: 1.0590x; 1.0590x over previous
//
#include <hip/hip_runtime.h>
#include <stdint.h>

// Problem constants (fixed by setup_inputs): B=2, C=32, H=W=D=96, N=30000
#define HWD 884736ull          // 96*96*96
#define NV 30000               // vertices per batch
#define AST 1032               // LDS A-tile row stride (shorts): 2064B

typedef __attribute__((ext_vector_type(8))) __bf16 bf16x8;
typedef __attribute__((ext_vector_type(4))) float f32x4;
typedef __attribute__((ext_vector_type(2))) float f32x2;
typedef __attribute__((ext_vector_type(4))) unsigned int uint4v;

__device__ __forceinline__ unsigned short f2bf(float f) {
    union { float f; unsigned int u; } v; v.f = f;
    unsigned int u = v.u;
    return (unsigned short)((u + 0x7FFFu + ((u >> 16) & 1u)) >> 16);  // RNE
}

__device__ __forceinline__ float bf2f(unsigned short s) {
    union { unsigned int u; float f; } v;
    v.u = ((unsigned int)s) << 16;
    return v.f;
}

// Unpack a uint holding two adjacent-channel bf16 values -> float2
__device__ __forceinline__ f32x2 up2(unsigned int u) {
    union { unsigned int u; float f; } lo, hi;
    lo.u = u << 16;
    hi.u = u & 0xFFFF0000u;
    f32x2 r; r.x = lo.f; r.y = hi.f;
    return r;
}

// Per-axis: replicate reference clamp/floor math for shifts {-1,0,1}, then fold
// into 4-wide window weights. Window start ws = clamp(x0_center-1, 0, 92).
__device__ __forceinline__ void axis_setup(float coord, float sc, int& wstart, float w[3][4]) {
    int i0[3], i1[3];
    float fr[3];
#pragma unroll
    for (int a = 0; a < 3; ++a) {
        float g = coord + (float)(a - 1) * sc;
        float ix = (g + 1.0f) * 0.5f * 95.0f;
        ix = fminf(fmaxf(ix, 0.0f), 95.0f);
        float fl = floorf(ix);
        int x0 = (int)fl;
        i0[a] = x0;
        i1[a] = min(x0 + 1, 95);
        fr[a] = ix - fl;
    }
    int ws = min(max(i0[1] - 1, 0), 92);
    wstart = ws;
#pragma unroll
    for (int a = 0; a < 3; ++a) {
        int d0 = min(max(i0[a] - ws, 0), 3);
        int d1 = min(max(i1[a] - ws, 0), 3);
        float f1 = fr[a], f0 = 1.0f - f1;
#pragma unroll
        for (int j = 0; j < 4; ++j)
            w[a][j] = (d0 == j ? f0 : 0.0f) + (d1 == j ? f1 : 0.0f);
    }
}

// Pack conv_w (32,32,1,27) fp32 -> bf16 B-fragments for mfma_f32_16x16x32_bf16.
// Layout (verified): element j of wp[(s*2+t)*64 + lane] is
// B[k = s*32 + (lane>>4)*8 + j][o = t*16 + (lane&15)]
__global__ __launch_bounds__(256) void prep_kernel(const float* __restrict__ cw,
                                                   unsigned short* __restrict__ Wp) {
    int gid = blockIdx.x * 256 + threadIdx.x;  // 0..32767
    int j = gid & 7;
    int l = (gid >> 3) & 63;
    int t = (gid >> 9) & 1;
    int s = gid >> 10;
    int kk = ((l >> 4) & 3) * 8 + j;
    int o = t * 16 + (l & 15);
    float v = 0.0f;
    if (kk < 27) v = cw[(size_t)o * 864 + s * 27 + kk];
    Wp[gid] = f2bf(v);
}

// (B,C,H,W,D) fp32 -> (B,H,W,D,C) bf16, LDS-staged for wide coalesced writes.
// One block per (b, z, y-pair): 192 x-positions x 32 channels = 12 KB out.
// Phase 1: float4 reads (L1 absorbs the per-channel line splits), bf16 convert,
//          scatter into LDS tile T[x][c] (stride 40 shorts keeps 16B alignment).
// Phase 2: each lane stores 16B (8 consecutive channels of one x) -> perfectly
//          coalesced dwordx4 stores, replacing the old 12x 2B scalar stores.
__global__ __launch_bounds__(256) void transpose_kernel(const float* __restrict__ vox,
                                                        unsigned short* __restrict__ voxT) {
    __shared__ unsigned short T[192 * 40];     // 15.4 KB
    int blk = blockIdx.x;                      // 0..9215 encodes (b, z, y2)
    int tid = threadIdx.x;
    int b = blk / 4608;
    int zy = blk - b * 4608;                   // z*48 + y2
    const float* src = vox + (size_t)b * 32 * HWD + (size_t)zy * 192;
#pragma unroll
    for (int i = 0; i < 6; ++i) {
        int j = i * 256 + tid;                 // 0..1535
        int c = j & 31;
        int x4 = j >> 5;                       // 0..47
        f32x4 v = __builtin_nontemporal_load((const f32x4*)(src + (size_t)c * HWD + x4 * 4));
#pragma unroll
        for (int k = 0; k < 4; ++k)
            T[(x4 * 4 + k) * 40 + c] = f2bf(v[k]);
    }
    __syncthreads();
    unsigned short* dst = voxT + (size_t)blk * 6144;
#pragma unroll
    for (int i = 0; i < 3; ++i) {
        int q = i * 256 + tid;                 // 0..767 (16B chunks)
        int x = q >> 2;
        int cg = (q & 3) * 8;
        uint4v val = *(const uint4v*)&T[x * 40 + cg];
        *(uint4v*)(dst + q * 8) = val;
    }
}

// Fused sample + GEMM. Block = 256 threads = 16 vertices x 16 channel-pairs.
// Each lane gathers TWO adjacent channels per voxel (uint loads: 4B/lane, a
// wave covers 4 vertices -> 4 full 64B lines per load instruction), does the
// separable x->y->z contraction in float2 (packed-fp32 capable), and writes
// its two 64B A-tile chunks with an XOR bank swizzle (k ^ (cp&7)) that the
// GEMM read side undoes. Waves 0/1 then run the 16x1024 @ 1024x32 MFMA GEMM.
__global__ __launch_bounds__(256) void fused_kernel(const unsigned short* __restrict__ voxT,
                                                    const float* __restrict__ verts,
                                                    const unsigned short* __restrict__ Wp,
                                                    const float* __restrict__ bias,
                                                    float* __restrict__ out) {
    __shared__ unsigned short At[16 * AST];
    int tid = threadIdx.x;
    int vl = tid >> 4;               // 0..15 vertex in block
    int cp = tid & 15;               // channel pair: channels {2cp, 2cp+1}
    int vg = (int)blockIdx.x * 16 + vl;   // 3750*16 = 60000 exactly

    const float* vp = verts + (size_t)vg * 3;
    float vx = vp[0], vy = vp[1], vz = vp[2];
    const float sc = 2.0f / 95.0f;
    int wsx, wsy, wsz;
    float wx[3][4], wy[3][4], wz[3][4];
    axis_setup(vx, sc, wsx, wx);  // x -> D axis (innermost spatial)
    axis_setup(vy, sc, wsy, wy);  // y -> W axis
    axis_setup(vz, sc, wsz, wz);  // z -> H axis
    int bb = (vg >= NV) ? 1 : 0;
    const unsigned short* vb = voxT + (size_t)bb * HWD * 32 + 2 * cp;

    f32x2 zz = {0.f, 0.f};
    f32x2 f[27];
#pragma unroll
    for (int k = 0; k < 27; ++k) f[k] = zz;

#pragma unroll
    for (int tz = 0; tz < 4; ++tz) {
        f32x2 ry[3][3];
#pragma unroll
        for (int bq = 0; bq < 3; ++bq)
#pragma unroll
            for (int a = 0; a < 3; ++a) ry[bq][a] = zz;
#pragma unroll
        for (int ty = 0; ty < 4; ++ty) {
            const unsigned short* row =
                vb + (((size_t)(wsz + tz) * 96 + (size_t)(wsy + ty)) * 96 + wsx) * 32;
            unsigned int u0 = *(const unsigned int*)(row);
            unsigned int u1 = *(const unsigned int*)(row + 32);
            unsigned int u2 = *(const unsigned int*)(row + 64);
            unsigned int u3 = *(const unsigned int*)(row + 96);
            f32x2 b0 = up2(u0), b1 = up2(u1), b2 = up2(u2), b3 = up2(u3);
#pragma unroll
            for (int a = 0; a < 3; ++a) {
                f32x2 r = b0 * wx[a][0] + b1 * wx[a][1] + b2 * wx[a][2] + b3 * wx[a][3];
#pragma unroll
                for (int bq = 0; bq < 3; ++bq)
                    ry[bq][a] += r * wy[bq][ty];
            }
        }
#pragma unroll
        for (int g = 0; g < 3; ++g)
#pragma unroll
            for (int bq = 0; bq < 3; ++bq)
#pragma unroll
                for (int a = 0; a < 3; ++a)
                    f[9 * a + 3 * bq + g] += wz[g][tz] * ry[bq][a];
    }

    // Pack both channels' 27 taps (+5 zero pad) to bf16 pairs.
    unsigned int pk0[16], pk1[16];
#pragma unroll
    for (int i = 0; i < 16; ++i) {
        float l0 = (2 * i < 27) ? f[2 * i].x : 0.0f;
        float h0 = (2 * i + 1 < 27) ? f[2 * i + 1].x : 0.0f;
        float l1 = (2 * i < 27) ? f[2 * i].y : 0.0f;
        float h1 = (2 * i + 1 < 27) ? f[2 * i + 1].y : 0.0f;
        pk0[i] = (unsigned int)f2bf(l0) | ((unsigned int)f2bf(h0) << 16);
        pk1[i] = (unsigned int)f2bf(l1) | ((unsigned int)f2bf(h1) << 16);
    }
    // Lane's region: A-tile row vl, shorts [cp*64, cp*64+64). Chunk k (16B) goes
    // to slot (k ^ (cp&7)) -> per store instruction the 16 lanes of a vertex hit
    // 8 distinct bank quads (2-way, free) instead of one (16-way).
    unsigned short* abase = &At[vl * AST + cp * 64];
    int e = cp & 7;
    {
        uint4v c0 = {pk0[0], pk0[1], pk0[2], pk0[3]};
        uint4v c1 = {pk0[4], pk0[5], pk0[6], pk0[7]};
        uint4v c2 = {pk0[8], pk0[9], pk0[10], pk0[11]};
        uint4v c3 = {pk0[12], pk0[13], pk0[14], pk0[15]};
        uint4v c4 = {pk1[0], pk1[1], pk1[2], pk1[3]};
        uint4v c5 = {pk1[4], pk1[5], pk1[6], pk1[7]};
        uint4v c6 = {pk1[8], pk1[9], pk1[10], pk1[11]};
        uint4v c7 = {pk1[12], pk1[13], pk1[14], pk1[15]};
        *(uint4v*)(abase + ((0 ^ e) << 3)) = c0;
        *(uint4v*)(abase + ((1 ^ e) << 3)) = c1;
        *(uint4v*)(abase + ((2 ^ e) << 3)) = c2;
        *(uint4v*)(abase + ((3 ^ e) << 3)) = c3;
        *(uint4v*)(abase + ((4 ^ e) << 3)) = c4;
        *(uint4v*)(abase + ((5 ^ e) << 3)) = c5;
        *(uint4v*)(abase + ((6 ^ e) << 3)) = c6;
        *(uint4v*)(abase + ((7 ^ e) << 3)) = c7;
    }

    __syncthreads();

    int wv = tid >> 6;               // wave id 0..3; waves 0,1 do the GEMM
    if (wv < 2) {
        int lane = tid & 63;
        int mrow = lane & 15, quad = lane >> 4;
        const bf16x8* wp = (const bf16x8*)Wp;
        f32x4 acc = {0.f, 0.f, 0.f, 0.f};
#pragma unroll 8
        for (int s = 0; s < 32; ++s) {
            // Global chunk G = s*4+quad; region cpg = G>>3, local k = G&7,
            // read at slot (k ^ (cpg&7)) to match the swizzled write.
            int cpg = s >> 1;
            int kk = ((s & 1) << 2) | quad;
            bf16x8 a = *(const bf16x8*)&At[mrow * AST + cpg * 64 + ((kk ^ (cpg & 7)) << 3)];
            bf16x8 b = wp[(s * 2 + wv) * 64 + lane];
            acc = __builtin_amdgcn_mfma_f32_16x16x32_bf16(a, b, acc, 0, 0, 0);
        }
        float bs = bias[wv * 16 + mrow];
#pragma unroll
        for (int r = 0; r < 4; ++r) {
            int v = (int)blockIdx.x * 16 + quad * 4 + r;
            out[(size_t)v * 32 + wv * 16 + mrow] = acc[r] + bs;
        }
    }
}

extern "C" void kernel_launch(void* const* d_in, const int* in_sizes, int n_in,
                              void* d_out, int out_size, void* d_ws, size_t ws_size,
                              hipStream_t stream) {
    const float* vox = (const float*)d_in[0];
    const float* verts = (const float*)d_in[1];
    const float* cw = (const float*)d_in[2];
    const float* cb = (const float*)d_in[3];
    float* out = (float*)d_out;

    // ws layout: Wp (64 KB) | voxT bf16 (2*HWD*32*2 = 113.25 MB). Total ~113.4 MB.
    unsigned short* Wp = (unsigned short*)d_ws;
    unsigned short* voxT = (unsigned short*)((char*)d_ws + 65536);

    hipLaunchKernelGGL(prep_kernel, dim3(128), dim3(256), 0, stream, cw, Wp);
    hipLaunchKernelGGL(transpose_kernel, dim3(9216), dim3(256), 0, stream, vox, voxT);
    hipLaunchKernelGGL(fused_kernel, dim3(3750), dim3(256), 0, stream,
                       voxT, verts, Wp, cb, out);
}

// Round 2
// 386.045 us; speedup vs baseline: 1.0890x; 1.0283x over previous
//
#include <hip/hip_runtime.h>
#include <stdint.h>

// Problem constants (fixed by setup_inputs): B=2, C=32, H=W=D=96, N=30000
#define HWD 884736ull          // 96*96*96
#define NV 30000               // vertices per batch
#define AST 1032               // LDS A-tile row stride (shorts): 2064B

typedef __attribute__((ext_vector_type(8))) __bf16 bf16x8;
typedef __attribute__((ext_vector_type(4))) float f32x4;
typedef __attribute__((ext_vector_type(2))) float f32x2;
typedef __attribute__((ext_vector_type(4))) unsigned int uint4v;

__device__ __forceinline__ unsigned short f2bf(float f) {
    union { float f; unsigned int u; } v; v.f = f;
    unsigned int u = v.u;
    return (unsigned short)((u + 0x7FFFu + ((u >> 16) & 1u)) >> 16);  // RNE (prep only)
}

// Native HW bf16 convert (RNE) -> compiler can emit v_cvt_pk_bf16_f32
__device__ __forceinline__ unsigned short bfc(float f) {
    __bf16 h = (__bf16)f;
    unsigned short u;
    __builtin_memcpy(&u, &h, 2);
    return u;
}

__device__ __forceinline__ unsigned int pkbf(float lo, float hi) {
    __bf16 a = (__bf16)lo, b = (__bf16)hi;
    unsigned short ua, ub;
    __builtin_memcpy(&ua, &a, 2);
    __builtin_memcpy(&ub, &b, 2);
    return (unsigned int)ua | ((unsigned int)ub << 16);
}

// Unpack a uint holding two adjacent-channel bf16 values -> float2
__device__ __forceinline__ f32x2 up2(unsigned int u) {
    union { unsigned int u; float f; } lo, hi;
    lo.u = u << 16;
    hi.u = u & 0xFFFF0000u;
    f32x2 r; r.x = lo.f; r.y = hi.f;
    return r;
}

// Per-axis: replicate reference clamp/floor math for shifts {-1,0,1}, then fold
// into 4-wide window weights. Window start ws = clamp(x0_center-1, 0, 92).
__device__ __forceinline__ void axis_setup(float coord, float sc, int& wstart, float w[3][4]) {
    int i0[3], i1[3];
    float fr[3];
#pragma unroll
    for (int a = 0; a < 3; ++a) {
        float g = coord + (float)(a - 1) * sc;
        float ix = (g + 1.0f) * 0.5f * 95.0f;
        ix = fminf(fmaxf(ix, 0.0f), 95.0f);
        float fl = floorf(ix);
        int x0 = (int)fl;
        i0[a] = x0;
        i1[a] = min(x0 + 1, 95);
        fr[a] = ix - fl;
    }
    int ws = min(max(i0[1] - 1, 0), 92);
    wstart = ws;
#pragma unroll
    for (int a = 0; a < 3; ++a) {
        int d0 = min(max(i0[a] - ws, 0), 3);
        int d1 = min(max(i1[a] - ws, 0), 3);
        float f1 = fr[a], f0 = 1.0f - f1;
#pragma unroll
        for (int j = 0; j < 4; ++j)
            w[a][j] = (d0 == j ? f0 : 0.0f) + (d1 == j ? f1 : 0.0f);
    }
}

// Pack conv_w (32,32,1,27) fp32 -> bf16 B-fragments for mfma_f32_16x16x32_bf16.
// Layout (verified): element j of wp[(s*2+t)*64 + lane] is
// B[k = s*32 + (lane>>4)*8 + j][o = t*16 + (lane&15)]
__global__ __launch_bounds__(256) void prep_kernel(const float* __restrict__ cw,
                                                   unsigned short* __restrict__ Wp) {
    int gid = blockIdx.x * 256 + threadIdx.x;  // 0..32767
    int j = gid & 7;
    int l = (gid >> 3) & 63;
    int t = (gid >> 9) & 1;
    int s = gid >> 10;
    int kk = ((l >> 4) & 3) * 8 + j;
    int o = t * 16 + (l & 15);
    float v = 0.0f;
    if (kk < 27) v = cw[(size_t)o * 864 + s * 27 + kk];
    Wp[gid] = f2bf(v);
}

// (B,C,H,W,D) fp32 -> (B,H,W,D,C) bf16, LDS-staged for wide coalesced IO.
// One block per (b, z, y-pair): 192 x-positions x 32 channels = 12 KB out.
// Phase 1: each 8-lane group reads 128B CONTIGUOUS from one channel row
//          (c = tid>>3, x4 = (tid&7)+8i) -> perfect coalescing, no L1 reliance.
//          Convert to bf16, scatter into LDS T[x][c] (stride 40: bank-clean).
// Phase 2: each lane stores 16B (8 consecutive channels of one x) -> perfectly
//          coalesced dwordx4 stores.
__global__ __launch_bounds__(256) void transpose_kernel(const float* __restrict__ vox,
                                                        unsigned short* __restrict__ voxT) {
    __shared__ unsigned short T[192 * 40];     // 15.4 KB
    int blk = blockIdx.x;                      // 0..9215 encodes (b, z, y2)
    int tid = threadIdx.x;
    int b = blk / 4608;
    int zy = blk - b * 4608;                   // z*48 + y2
    const float* src = vox + (size_t)b * 32 * HWD + (size_t)zy * 192;
    int c = tid >> 3;                          // 0..31
    int xs = tid & 7;                          // x4 slot within 8-lane group
    const float* srcc = src + (size_t)c * HWD;
#pragma unroll
    for (int i = 0; i < 6; ++i) {
        int x4 = xs + 8 * i;                   // 0..47
        f32x4 v = *(const f32x4*)(srcc + x4 * 4);
#pragma unroll
        for (int k = 0; k < 4; ++k)
            T[(x4 * 4 + k) * 40 + c] = bfc(v[k]);
    }
    __syncthreads();
    unsigned short* dst = voxT + (size_t)blk * 6144;
#pragma unroll
    for (int i = 0; i < 3; ++i) {
        int q = i * 256 + tid;                 // 0..767 (16B chunks)
        int x = q >> 2;
        int cg = (q & 3) * 8;
        uint4v val = *(const uint4v*)&T[x * 40 + cg];
        *(uint4v*)(dst + q * 8) = val;
    }
}

// Fused sample + GEMM. Block = 256 threads = 16 vertices x 16 channel-pairs.
// Each lane gathers TWO adjacent channels per voxel (uint loads: 4B/lane, a
// wave covers 4 vertices -> 4 full 64B lines per load instruction), does the
// separable x->y->z contraction in float2, and writes its two 64B A-tile
// chunks with an XOR bank swizzle (k ^ (cp&7)) that the GEMM read side undoes.
// Waves 0/1 then run the 16x1024 @ 1024x32 MFMA GEMM.
__global__ __launch_bounds__(256) void fused_kernel(const unsigned short* __restrict__ voxT,
                                                    const float* __restrict__ verts,
                                                    const unsigned short* __restrict__ Wp,
                                                    const float* __restrict__ bias,
                                                    float* __restrict__ out) {
    __shared__ unsigned short At[16 * AST];
    int tid = threadIdx.x;
    int vl = tid >> 4;               // 0..15 vertex in block
    int cp = tid & 15;               // channel pair: channels {2cp, 2cp+1}
    int vg = (int)blockIdx.x * 16 + vl;   // 3750*16 = 60000 exactly

    const float* vp = verts + (size_t)vg * 3;
    float vx = vp[0], vy = vp[1], vz = vp[2];
    const float sc = 2.0f / 95.0f;
    int wsx, wsy, wsz;
    float wx[3][4], wy[3][4], wz[3][4];
    axis_setup(vx, sc, wsx, wx);  // x -> D axis (innermost spatial)
    axis_setup(vy, sc, wsy, wy);  // y -> W axis
    axis_setup(vz, sc, wsz, wz);  // z -> H axis
    int bb = (vg >= NV) ? 1 : 0;
    const unsigned short* vb = voxT + (size_t)bb * HWD * 32 + 2 * cp;

    f32x2 zz = {0.f, 0.f};
    f32x2 f[27];
#pragma unroll
    for (int k = 0; k < 27; ++k) f[k] = zz;

#pragma unroll
    for (int tz = 0; tz < 4; ++tz) {
        f32x2 ry[3][3];
#pragma unroll
        for (int bq = 0; bq < 3; ++bq)
#pragma unroll
            for (int a = 0; a < 3; ++a) ry[bq][a] = zz;
#pragma unroll
        for (int ty = 0; ty < 4; ++ty) {
            const unsigned short* row =
                vb + (((size_t)(wsz + tz) * 96 + (size_t)(wsy + ty)) * 96 + wsx) * 32;
            unsigned int u0 = *(const unsigned int*)(row);
            unsigned int u1 = *(const unsigned int*)(row + 32);
            unsigned int u2 = *(const unsigned int*)(row + 64);
            unsigned int u3 = *(const unsigned int*)(row + 96);
            f32x2 b0 = up2(u0), b1 = up2(u1), b2 = up2(u2), b3 = up2(u3);
#pragma unroll
            for (int a = 0; a < 3; ++a) {
                f32x2 r = b0 * wx[a][0] + b1 * wx[a][1] + b2 * wx[a][2] + b3 * wx[a][3];
#pragma unroll
                for (int bq = 0; bq < 3; ++bq)
                    ry[bq][a] += r * wy[bq][ty];
            }
        }
#pragma unroll
        for (int g = 0; g < 3; ++g)
#pragma unroll
            for (int bq = 0; bq < 3; ++bq)
#pragma unroll
                for (int a = 0; a < 3; ++a)
                    f[9 * a + 3 * bq + g] += wz[g][tz] * ry[bq][a];
    }

    // Pack both channels' 27 taps (+5 zero pad) to bf16 pairs (HW cvt_pk).
    unsigned int pk0[16], pk1[16];
#pragma unroll
    for (int i = 0; i < 16; ++i) {
        float l0 = (2 * i < 27) ? f[2 * i].x : 0.0f;
        float h0 = (2 * i + 1 < 27) ? f[2 * i + 1].x : 0.0f;
        float l1 = (2 * i < 27) ? f[2 * i].y : 0.0f;
        float h1 = (2 * i + 1 < 27) ? f[2 * i + 1].y : 0.0f;
        pk0[i] = pkbf(l0, h0);
        pk1[i] = pkbf(l1, h1);
    }
    // Lane's region: A-tile row vl, shorts [cp*64, cp*64+64). Chunk k (16B) goes
    // to slot (k ^ (cp&7)) -> per store instruction the lanes spread evenly
    // across all bank groups (balanced b128 access).
    unsigned short* abase = &At[vl * AST + cp * 64];
    int e = cp & 7;
    {
        uint4v c0 = {pk0[0], pk0[1], pk0[2], pk0[3]};
        uint4v c1 = {pk0[4], pk0[5], pk0[6], pk0[7]};
        uint4v c2 = {pk0[8], pk0[9], pk0[10], pk0[11]};
        uint4v c3 = {pk0[12], pk0[13], pk0[14], pk0[15]};
        uint4v c4 = {pk1[0], pk1[1], pk1[2], pk1[3]};
        uint4v c5 = {pk1[4], pk1[5], pk1[6], pk1[7]};
        uint4v c6 = {pk1[8], pk1[9], pk1[10], pk1[11]};
        uint4v c7 = {pk1[12], pk1[13], pk1[14], pk1[15]};
        *(uint4v*)(abase + ((0 ^ e) << 3)) = c0;
        *(uint4v*)(abase + ((1 ^ e) << 3)) = c1;
        *(uint4v*)(abase + ((2 ^ e) << 3)) = c2;
        *(uint4v*)(abase + ((3 ^ e) << 3)) = c3;
        *(uint4v*)(abase + ((4 ^ e) << 3)) = c4;
        *(uint4v*)(abase + ((5 ^ e) << 3)) = c5;
        *(uint4v*)(abase + ((6 ^ e) << 3)) = c6;
        *(uint4v*)(abase + ((7 ^ e) << 3)) = c7;
    }

    __syncthreads();

    int wv = tid >> 6;               // wave id 0..3; waves 0,1 do the GEMM
    if (wv < 2) {
        int lane = tid & 63;
        int mrow = lane & 15, quad = lane >> 4;
        const bf16x8* wp = (const bf16x8*)Wp;
        f32x4 acc = {0.f, 0.f, 0.f, 0.f};
#pragma unroll 8
        for (int s = 0; s < 32; ++s) {
            // Global chunk G = s*4+quad; region cpg = G>>3, local k = G&7,
            // read at slot (k ^ (cpg&7)) to match the swizzled write.
            int cpg = s >> 1;
            int kk = ((s & 1) << 2) | quad;
            bf16x8 a = *(const bf16x8*)&At[mrow * AST + cpg * 64 + ((kk ^ (cpg & 7)) << 3)];
            bf16x8 b = wp[(s * 2 + wv) * 64 + lane];
            acc = __builtin_amdgcn_mfma_f32_16x16x32_bf16(a, b, acc, 0, 0, 0);
        }
        float bs = bias[wv * 16 + mrow];
#pragma unroll
        for (int r = 0; r < 4; ++r) {
            int v = (int)blockIdx.x * 16 + quad * 4 + r;
            out[(size_t)v * 32 + wv * 16 + mrow] = acc[r] + bs;
        }
    }
}

extern "C" void kernel_launch(void* const* d_in, const int* in_sizes, int n_in,
                              void* d_out, int out_size, void* d_ws, size_t ws_size,
                              hipStream_t stream) {
    const float* vox = (const float*)d_in[0];
    const float* verts = (const float*)d_in[1];
    const float* cw = (const float*)d_in[2];
    const float* cb = (const float*)d_in[3];
    float* out = (float*)d_out;

    // ws layout: Wp (64 KB) | voxT bf16 (2*HWD*32*2 = 113.25 MB). Total ~113.4 MB.
    unsigned short* Wp = (unsigned short*)d_ws;
    unsigned short* voxT = (unsigned short*)((char*)d_ws + 65536);

    hipLaunchKernelGGL(prep_kernel, dim3(128), dim3(256), 0, stream, cw, Wp);
    hipLaunchKernelGGL(transpose_kernel, dim3(9216), dim3(256), 0, stream, vox, voxT);
    hipLaunchKernelGGL(fused_kernel, dim3(3750), dim3(256), 0, stream,
                       voxT, verts, Wp, cb, out);
}